// Round 1
// baseline (269.958 us; speedup 1.0000x reference)
//
#include <hip/hip_runtime.h>
#include <math.h>

// Problem constants
#define B_    32
#define S_    2048
#define CIN_  256
#define COUT_ 256
#define K_    16
#define TOUT_ 2033   // S - K + 1
#define RTOT_ 4096   // CIN * K reduction length

typedef __bf16 bf16x4 __attribute__((ext_vector_type(4)));
typedef __bf16 bf16x8 __attribute__((ext_vector_type(8)));
typedef float  f32x4  __attribute__((ext_vector_type(4)));

#define GLOBAL_AS __attribute__((address_space(1)))
#define LDS_AS    __attribute__((address_space(3)))

__device__ __forceinline__ void gload_lds16(const void* g, void* l) {
  // async global -> LDS: per-lane global gather, LDS dest = wave-uniform base + lane*16
  __builtin_amdgcn_global_load_lds((const GLOBAL_AS void*)g, (LDS_AS void*)l, 16, 0, 0);
}

// ---------------------------------------------------------------------------
// Build B^T in bf16:  wt[o][kk*256 + i] = cos(ph[kk])*w_real[o][i][kk]
//                                        - sin(ph[kk])*w_imag[o][i][kk]
// Row-major [COUT][RTOT] = 2 MB workspace (keep ws footprint tiny).
// ---------------------------------------------------------------------------
__global__ void __launch_bounds__(256) build_wt_kernel(const float* __restrict__ wr,
                                                       const float* __restrict__ wi,
                                                       const float* __restrict__ ph,
                                                       __bf16* __restrict__ wt) {
  int t = blockIdx.x * 256 + threadIdx.x;   // 65536 threads: one per (o,i)
  int o = t >> 8, i = t & 255;
  const float4* wr4 = (const float4*)(wr + (size_t)(o * CIN_ + i) * K_);
  const float4* wi4 = (const float4*)(wi + (size_t)(o * CIN_ + i) * K_);
  float re[16], im[16];
  #pragma unroll
  for (int v = 0; v < 4; v++) {
    float4 a = wr4[v];
    re[4*v+0]=a.x; re[4*v+1]=a.y; re[4*v+2]=a.z; re[4*v+3]=a.w;
    float4 b = wi4[v];
    im[4*v+0]=b.x; im[4*v+1]=b.y; im[4*v+2]=b.z; im[4*v+3]=b.w;
  }
  #pragma unroll
  for (int kk = 0; kk < K_; kk++) {
    float p = ph[kk];
    wt[(size_t)o * RTOT_ + kk * CIN_ + i] = (__bf16)(cosf(p)*re[kk] - sinf(p)*im[kk]);
  }
}

// ---------------------------------------------------------------------------
// Main: implicit-GEMM conv with tap-resident A tile, software-pipelined
// (T3+T4+T5): linear step index j = ic*16+kk (0..127).
//  - Bs: 4-buffer ring (4 x 8 KB), prefetch depth 2 (iter j stages j+2).
//  - One raw s_barrier per iter, fused with counted s_waitcnt vmcnt(2):
//    B(j+1)'s 2 loads (older) are guaranteed complete, B(j+2)'s 2 stay in
//    flight across the barrier. vmcnt(0) only in the 2 peeled final iters.
//  - Buffer-race ledger (single barrier/iter => waves skew <= 1 iter):
//    writes buf (j+2)&3, reads buf j&3, laggard reads (j-1)&3 - distinct mod 4.
//  - As re-staged at ic boundaries (8/128 iters) under an explicit
//    lgkmcnt(0)+s_barrier fence (conservative drain bubble accepted there).
//  - s_setprio(1) around the 16-MFMA cluster.
// ---------------------------------------------------------------------------
__global__ void __launch_bounds__(256, 3) conv_mfma_kernel(const float* __restrict__ xg,
                                                           const __bf16* __restrict__ wt,
                                                           float* __restrict__ out) {
  __shared__ __align__(16) __bf16 As[144 * 32];       // [row t-local][32 ch] 9 KB
  __shared__ __align__(16) __bf16 Bs[4][128 * 32];    // ring of [row o-local][32 k] 4x8 KB

  const int bx = blockIdx.x;
  const int nb = bx & 1;          // o-block 0..1
  const int mb = (bx >> 1) & 15;  // t-block 0..15
  const int b  = bx >> 5;         // batch   0..31

  const int tid  = threadIdx.x;
  const int w    = tid >> 6;
  const int lane = tid & 63;
  const int wm   = w >> 1, wn = w & 1;
  const int n16  = lane & 15, q = lane >> 4;

  const int t0 = mb * 128;
  const int o0 = nb * 128;

  const float* xbase = xg + (size_t)b * (S_ * CIN_);

  // A staging geometry (reg round-trip): thread -> (row sr, 4 fp32 at col sc)
  const int sr = tid >> 3;        // 0..31
  const int sc = (tid & 7) * 4;   // fp32/bf16 col offset
  // B staging geometry (global_load_lds, 16B/lane): wave w, issue p covers
  // rows p*64 + w*16 .. +16
  const int br = w * 16 + (lane >> 2);
  const int bc = (lane & 3) * 8;

  f32x4 acc[4][4];
  #pragma unroll
  for (int im_ = 0; im_ < 4; im_++)
    #pragma unroll
    for (int in_ = 0; in_ < 4; in_++)
      acc[im_][in_] = {0.f, 0.f, 0.f, 0.f};

  // ---- Stage A for channel group ic: rows 0..143 (x rows t0.., clamped) ----
  auto stage_a = [&](int ic) {
    const float* xcol = xbase + ic * 32 + sc;
    #pragma unroll
    for (int p = 0; p < 4; p++) {
      int r = p * 32 + sr;
      int rg = t0 + r; rg = (rg < S_) ? rg : (S_ - 1);
      float4 v = *(const float4*)(xcol + (size_t)rg * CIN_);
      bf16x4 o4; o4[0]=(__bf16)v.x; o4[1]=(__bf16)v.y; o4[2]=(__bf16)v.z; o4[3]=(__bf16)v.w;
      *(bf16x4*)(As + r * 32 + sc) = o4;
    }
    if (tid < 128) {  // tail rows 128..143
      int r = 128 + sr;
      int rg = t0 + r; rg = (rg < S_) ? rg : (S_ - 1);
      float4 v = *(const float4*)(xcol + (size_t)rg * CIN_);
      bf16x4 o4; o4[0]=(__bf16)v.x; o4[1]=(__bf16)v.y; o4[2]=(__bf16)v.z; o4[3]=(__bf16)v.w;
      *(bf16x4*)(As + r * 32 + sc) = o4;
    }
  };

  // ---- Stage B chunk for step j into ring buffer j&3 (2 gload_lds/wave) ----
  auto stage_b = [&](int j) {
    const int kk = j & 15;
    const int i0 = (j >> 4) * 32;
    const __bf16* wcol = wt + (size_t)kk * CIN_ + i0 + bc;
    __bf16* dst = &Bs[j & 3][(w * 16) * 32];
    #pragma unroll
    for (int p = 0; p < 2; p++) {
      int orow = o0 + p * 64 + br;
      gload_lds16(wcol + (size_t)orow * RTOT_, (void*)(dst + p * 64 * 32));
    }
  };

  // ---- Prologue: A(ic=0) + B(0), B(1); wait B(0) landed, keep B(1) in flight
  stage_a(0);
  stage_b(0);
  stage_b(1);
  asm volatile("s_waitcnt vmcnt(2) lgkmcnt(0)\n\ts_barrier" ::: "memory");

  for (int j = 0; j < 128; ++j) {
    if (j + 2 < 128) stage_b(j + 2);   // prefetch depth 2 (wave-uniform guard)

    const int kk = j & 15;
    const __bf16* bsr = Bs[j & 3];
    bf16x8 af[4], bfrag[4];
    #pragma unroll
    for (int jm = 0; jm < 4; jm++) {
      int row = kk + wm * 64 + jm * 16 + n16;    // A[m=lane&15][k=q*8+j]
      af[jm] = *(const bf16x8*)(As + row * 32 + q * 8);
    }
    #pragma unroll
    for (int jn = 0; jn < 4; jn++) {
      int row = wn * 64 + jn * 16 + n16;         // B^T[n=lane&15][k=q*8+j]
      bfrag[jn] = *(const bf16x8*)(bsr + row * 32 + q * 8);
    }

    __builtin_amdgcn_s_setprio(1);
    #pragma unroll
    for (int jm = 0; jm < 4; jm++)
      #pragma unroll
      for (int jn = 0; jn < 4; jn++)
        acc[jm][jn] = __builtin_amdgcn_mfma_f32_16x16x32_bf16(af[jm], bfrag[jn], acc[jm][jn], 0, 0, 0);
    __builtin_amdgcn_s_setprio(0);

    if (j == 127) break;               // last step: no barrier needed

    // Counted end-of-iter wait: B(j+1) complete (older), B(j+2) stays in
    // flight. j==126 issued nothing this iter -> must drain B(127) fully.
    if (j <= 125) asm volatile("s_waitcnt vmcnt(2)\n\ts_barrier" ::: "memory");
    else          asm volatile("s_waitcnt vmcnt(0)\n\ts_barrier" ::: "memory");

    if ((kk == 15)) {
      // ic boundary: all waves' As reads for this ic are pre-barrier -> safe
      // to overwrite. Fence ds_writes with lgkmcnt(0) before releasing waves.
      stage_a((j + 1) >> 4);
      asm volatile("s_waitcnt lgkmcnt(0)\n\ts_barrier" ::: "memory");
    }
  }

  // ---- Epilogue: C/D layout col = lane&15, row = (lane>>4)*4 + reg ----
  float* obase = out + (size_t)b * TOUT_ * COUT_;
  #pragma unroll
  for (int jm = 0; jm < 4; jm++) {
    #pragma unroll
    for (int r = 0; r < 4; r++) {
      int t = t0 + wm * 64 + jm * 16 + q * 4 + r;
      if (t < TOUT_) {
        float* orow = obase + (size_t)t * COUT_ + o0 + wn * 64 + n16;
        #pragma unroll
        for (int jn = 0; jn < 4; jn++)
          orow[jn * 16] = acc[jm][jn][r];
      }
    }
  }
}

// ---------------------------------------------------------------------------
extern "C" void kernel_launch(void* const* d_in, const int* in_sizes, int n_in,
                              void* d_out, int out_size, void* d_ws, size_t ws_size,
                              hipStream_t stream) {
  const float* x  = (const float*)d_in[0];
  const float* wr = (const float*)d_in[1];
  const float* wi = (const float*)d_in[2];
  const float* ph = (const float*)d_in[3];
  float* out = (float*)d_out;

  __bf16* wt = (__bf16*)d_ws;  // 2 MB only

  build_wt_kernel<<<dim3((COUT_ * CIN_) / 256), dim3(256), 0, stream>>>(wr, wi, ph, wt);
  conv_mfma_kernel<<<dim3(B_ * 16 * 2), dim3(256), 0, stream>>>(x, wt, out);
}

// Round 2
// 238.364 us; speedup vs baseline: 1.1325x; 1.1325x over previous
//
#include <hip/hip_runtime.h>
#include <math.h>

// Problem constants
#define B_    32
#define S_    2048
#define CIN_  256
#define COUT_ 256
#define K_    16
#define TOUT_ 2033   // S - K + 1
#define RTOT_ 4096   // CIN * K reduction length

typedef __bf16 bf16x4 __attribute__((ext_vector_type(4)));
typedef __bf16 bf16x8 __attribute__((ext_vector_type(8)));
typedef float  f32x4  __attribute__((ext_vector_type(4)));

#define GLOBAL_AS __attribute__((address_space(1)))
#define LDS_AS    __attribute__((address_space(3)))

__device__ __forceinline__ void gload_lds16(const void* g, void* l) {
  // async global -> LDS: per-lane global gather, LDS dest = wave-uniform base + lane*16
  __builtin_amdgcn_global_load_lds((const GLOBAL_AS void*)g, (LDS_AS void*)l, 16, 0, 0);
}

// ---------------------------------------------------------------------------
// Build B^T in bf16:  wt[o][kk*256 + i] = cos(ph[kk])*w_real[o][i][kk]
//                                        - sin(ph[kk])*w_imag[o][i][kk]
// Row-major [COUT][RTOT] = 2 MB workspace (keep ws footprint tiny).
// ---------------------------------------------------------------------------
__global__ void __launch_bounds__(256) build_wt_kernel(const float* __restrict__ wr,
                                                       const float* __restrict__ wi,
                                                       const float* __restrict__ ph,
                                                       __bf16* __restrict__ wt) {
  int t = blockIdx.x * 256 + threadIdx.x;   // 65536 threads: one per (o,i)
  int o = t >> 8, i = t & 255;
  const float4* wr4 = (const float4*)(wr + (size_t)(o * CIN_ + i) * K_);
  const float4* wi4 = (const float4*)(wi + (size_t)(o * CIN_ + i) * K_);
  float re[16], im[16];
  #pragma unroll
  for (int v = 0; v < 4; v++) {
    float4 a = wr4[v];
    re[4*v+0]=a.x; re[4*v+1]=a.y; re[4*v+2]=a.z; re[4*v+3]=a.w;
    float4 b = wi4[v];
    im[4*v+0]=b.x; im[4*v+1]=b.y; im[4*v+2]=b.z; im[4*v+3]=b.w;
  }
  #pragma unroll
  for (int kk = 0; kk < K_; kk++) {
    float p = ph[kk];
    wt[(size_t)o * RTOT_ + kk * CIN_ + i] = (__bf16)(cosf(p)*re[kk] - sinf(p)*im[kk]);
  }
}

// ---------------------------------------------------------------------------
// Main: implicit-GEMM conv with tap-resident A tile, software-pipelined
// (T3+T4+T5+T14): linear step index j = ic*16+kk (0..127).
//  - Bs: 3-buffer ring (3 x 8 KB), prefetch depth 2 (iter j stages j+2).
//    LDS total 33792 B -> 4 blocks/CU (round-1 regression was the 4-ring's
//    41984 B capping residency at 3 blocks/CU with a grid of exactly 4/CU).
//  - One raw s_barrier per iter fused with counted s_waitcnt vmcnt(2):
//    B(j+1)'s 2 loads (older, in-order) complete, B(j+2)'s 2 stay in flight.
//    vmcnt(0) only at the 2 peeled final iters.
//  - Ring-3 race ledger (single barrier/iter => all waves in same iter j):
//    writes buf (j+2)%3, reads buf j%3 (distinct); old contents of
//    (j+2)%3 = B(j-1), whose reads completed before barrier_{j-1}.
//  - T14 A-restage: x float4 loads issued at top of kk==14 iter (before
//    stage_b so end-of-iter vmcnt(2) retires them in-order while keeping
//    B in flight); ic boundary only does cvt+ds_write+lgkmcnt(0)+barrier.
//  - s_setprio(1) around the 16-MFMA cluster.
// ---------------------------------------------------------------------------
__global__ void __launch_bounds__(256, 4) conv_mfma_kernel(const float* __restrict__ xg,
                                                           const __bf16* __restrict__ wt,
                                                           float* __restrict__ out) {
  __shared__ __align__(16) __bf16 As[144 * 32];       // [row t-local][32 ch] 9216 B
  __shared__ __align__(16) __bf16 Bs[3][128 * 32];    // ring of [row o-local][32 k] 3x8192 B

  const int bx = blockIdx.x;
  const int nb = bx & 1;          // o-block 0..1
  const int mb = (bx >> 1) & 15;  // t-block 0..15
  const int b  = bx >> 5;         // batch   0..31

  const int tid  = threadIdx.x;
  const int w    = tid >> 6;
  const int lane = tid & 63;
  const int wm   = w >> 1, wn = w & 1;
  const int n16  = lane & 15, q = lane >> 4;

  const int t0 = mb * 128;
  const int o0 = nb * 128;

  const float* xbase = xg + (size_t)b * (S_ * CIN_);

  // A staging geometry (reg round-trip): thread -> (row sr, 4 fp32 at col sc)
  const int sr = tid >> 3;        // 0..31
  const int sc = (tid & 7) * 4;   // fp32/bf16 col offset
  // B staging geometry (global_load_lds, 16B/lane): wave w, issue p covers
  // rows p*64 + w*16 .. +16
  const int br = w * 16 + (lane >> 2);
  const int bc = (lane & 3) * 8;

  f32x4 acc[4][4];
  #pragma unroll
  for (int im_ = 0; im_ < 4; im_++)
    #pragma unroll
    for (int in_ = 0; in_ < 4; in_++)
      acc[im_][in_] = {0.f, 0.f, 0.f, 0.f};

  // ---- T14 A staging: issue global->reg early, commit reg->LDS at boundary
  float4 a_pref[5];   // statically indexed only (rule #20)

  auto issue_a = [&](int ic) {
    const float* xcol = xbase + ic * 32 + sc;
    #pragma unroll
    for (int p = 0; p < 4; p++) {
      int r = p * 32 + sr;
      int rg = t0 + r; rg = (rg < S_) ? rg : (S_ - 1);
      a_pref[p] = *(const float4*)(xcol + (size_t)rg * CIN_);
    }
    if (tid < 128) {  // tail rows 128..143 (waves 0,1 only; vmcnt is per-wave)
      int r = 128 + sr;
      int rg = t0 + r; rg = (rg < S_) ? rg : (S_ - 1);
      a_pref[4] = *(const float4*)(xcol + (size_t)rg * CIN_);
    }
  };
  auto commit_a = [&]() {
    #pragma unroll
    for (int p = 0; p < 4; p++) {
      int r = p * 32 + sr;
      float4 v = a_pref[p];
      bf16x4 o4; o4[0]=(__bf16)v.x; o4[1]=(__bf16)v.y; o4[2]=(__bf16)v.z; o4[3]=(__bf16)v.w;
      *(bf16x4*)(As + r * 32 + sc) = o4;
    }
    if (tid < 128) {
      int r = 128 + sr;
      float4 v = a_pref[4];
      bf16x4 o4; o4[0]=(__bf16)v.x; o4[1]=(__bf16)v.y; o4[2]=(__bf16)v.z; o4[3]=(__bf16)v.w;
      *(bf16x4*)(As + r * 32 + sc) = o4;
    }
  };

  // ---- Stage B chunk for step j into ring buffer buf (2 gload_lds/wave) ----
  auto stage_b = [&](int j, int buf) {
    const int kk = j & 15;
    const int i0 = (j >> 4) * 32;
    const __bf16* wcol = wt + (size_t)kk * CIN_ + i0 + bc;
    __bf16* dst = &Bs[0][0] + buf * (128 * 32) + (w * 16) * 32;
    #pragma unroll
    for (int p = 0; p < 2; p++) {
      int orow = o0 + p * 64 + br;
      gload_lds16(wcol + (size_t)orow * RTOT_, (void*)(dst + p * 64 * 32));
    }
  };

  // ---- Prologue: A(ic=0) + B(0), B(1); wait B(0) landed, keep B(1) in flight
  issue_a(0);
  commit_a();          // compiler inserts the vmcnt waits for a_pref uses
  stage_b(0, 0);
  stage_b(1, 1);
  asm volatile("s_waitcnt vmcnt(2) lgkmcnt(0)\n\ts_barrier" ::: "memory");

  int jr = 0;   // read buffer  = j % 3
  int jw = 2;   // write buffer = (j+2) % 3
  #pragma unroll 1
  for (int j = 0; j < 128; ++j) {
    const int kk = j & 15;

    // T14: issue next-ic A loads BEFORE stage_b so this iter's vmcnt(2)
    // retires them (in-order) while leaving B(j+2) in flight.
    if (kk == 14 && j != 126) issue_a((j >> 4) + 1);
    if (j + 2 < 128) stage_b(j + 2, jw);   // prefetch depth 2 (wave-uniform)

    const __bf16* bsr = &Bs[0][0] + jr * (128 * 32);
    bf16x8 af[4], bfrag[4];
    #pragma unroll
    for (int jm = 0; jm < 4; jm++) {
      int row = kk + wm * 64 + jm * 16 + n16;    // A[m=lane&15][k=q*8+j]
      af[jm] = *(const bf16x8*)(As + row * 32 + q * 8);
    }
    #pragma unroll
    for (int jn = 0; jn < 4; jn++) {
      int row = wn * 64 + jn * 16 + n16;         // B^T[n=lane&15][k=q*8+j]
      bfrag[jn] = *(const bf16x8*)(bsr + row * 32 + q * 8);
    }

    __builtin_amdgcn_s_setprio(1);
    #pragma unroll
    for (int jm = 0; jm < 4; jm++)
      #pragma unroll
      for (int jn = 0; jn < 4; jn++)
        acc[jm][jn] = __builtin_amdgcn_mfma_f32_16x16x32_bf16(af[jm], bfrag[jn], acc[jm][jn], 0, 0, 0);
    __builtin_amdgcn_s_setprio(0);

    if (j == 127) break;               // last step: no barrier needed

    // Counted end-of-iter wait: B(j+1) complete (older), B(j+2) stays in
    // flight. j==126 issued nothing this iter -> must drain B(127) fully.
    if (j <= 125) asm volatile("s_waitcnt vmcnt(2)\n\ts_barrier" ::: "memory");
    else          asm volatile("s_waitcnt vmcnt(0)\n\ts_barrier" ::: "memory");

    if (kk == 15) {
      // ic boundary: all waves' As reads for this ic were pre-barrier -> safe
      // to overwrite. a_pref regs retired since the kk==14 iter's vmcnt(2).
      commit_a();
      asm volatile("s_waitcnt lgkmcnt(0)\n\ts_barrier" ::: "memory");
    }

    jr = (jr == 2) ? 0 : jr + 1;
    jw = (jw == 2) ? 0 : jw + 1;
  }

  // ---- Epilogue: C/D layout col = lane&15, row = (lane>>4)*4 + reg ----
  float* obase = out + (size_t)b * TOUT_ * COUT_;
  #pragma unroll
  for (int jm = 0; jm < 4; jm++) {
    #pragma unroll
    for (int r = 0; r < 4; r++) {
      int t = t0 + wm * 64 + jm * 16 + q * 4 + r;
      if (t < TOUT_) {
        float* orow = obase + (size_t)t * COUT_ + o0 + wn * 64 + n16;
        #pragma unroll
        for (int jn = 0; jn < 4; jn++)
          orow[jn * 16] = acc[jm][jn][r];
      }
    }
  }
}

// ---------------------------------------------------------------------------
extern "C" void kernel_launch(void* const* d_in, const int* in_sizes, int n_in,
                              void* d_out, int out_size, void* d_ws, size_t ws_size,
                              hipStream_t stream) {
  const float* x  = (const float*)d_in[0];
  const float* wr = (const float*)d_in[1];
  const float* wi = (const float*)d_in[2];
  const float* ph = (const float*)d_in[3];
  float* out = (float*)d_out;

  __bf16* wt = (__bf16*)d_ws;  // 2 MB only

  build_wt_kernel<<<dim3((COUT_ * CIN_) / 256), dim3(256), 0, stream>>>(wr, wi, ph, wt);
  conv_mfma_kernel<<<dim3(B_ * 16 * 2), dim3(256), 0, stream>>>(x, wt, out);
}

// Round 3
// 221.539 us; speedup vs baseline: 1.2186x; 1.0759x over previous
//
#include <hip/hip_runtime.h>
#include <math.h>

// Problem constants
#define B_    32
#define S_    2048
#define CIN_  256
#define COUT_ 256
#define K_    16
#define TOUT_ 2033   // S - K + 1
#define RTOT_ 4096   // CIN * K reduction length

typedef __bf16 bf16x4 __attribute__((ext_vector_type(4)));
typedef __bf16 bf16x8 __attribute__((ext_vector_type(8)));
typedef float  f32x4  __attribute__((ext_vector_type(4)));

#define GLOBAL_AS __attribute__((address_space(1)))
#define LDS_AS    __attribute__((address_space(3)))

__device__ __forceinline__ void gload_lds16(const void* g, void* l) {
  // async global -> LDS: per-lane global gather, LDS dest = wave-uniform base + lane*16
  __builtin_amdgcn_global_load_lds((const GLOBAL_AS void*)g, (LDS_AS void*)l, 16, 0, 0);
}

// ---------------------------------------------------------------------------
// Build B^T in bf16:  wt[o][kk*256 + i] = cos(ph[kk])*w_real[o][i][kk]
//                                        - sin(ph[kk])*w_imag[o][i][kk]
// Row-major [COUT][RTOT] = 2 MB workspace (keep ws footprint tiny).
// ---------------------------------------------------------------------------
__global__ void __launch_bounds__(256) build_wt_kernel(const float* __restrict__ wr,
                                                       const float* __restrict__ wi,
                                                       const float* __restrict__ ph,
                                                       __bf16* __restrict__ wt) {
  int t = blockIdx.x * 256 + threadIdx.x;   // 65536 threads: one per (o,i)
  int o = t >> 8, i = t & 255;
  const float4* wr4 = (const float4*)(wr + (size_t)(o * CIN_ + i) * K_);
  const float4* wi4 = (const float4*)(wi + (size_t)(o * CIN_ + i) * K_);
  float re[16], im[16];
  #pragma unroll
  for (int v = 0; v < 4; v++) {
    float4 a = wr4[v];
    re[4*v+0]=a.x; re[4*v+1]=a.y; re[4*v+2]=a.z; re[4*v+3]=a.w;
    float4 b = wi4[v];
    im[4*v+0]=b.x; im[4*v+1]=b.y; im[4*v+2]=b.z; im[4*v+3]=b.w;
  }
  #pragma unroll
  for (int kk = 0; kk < K_; kk++) {
    float p = ph[kk];
    wt[(size_t)o * RTOT_ + kk * CIN_ + i] = (__bf16)(cosf(p)*re[kk] - sinf(p)*im[kk]);
  }
}

// ---------------------------------------------------------------------------
// Main: implicit-GEMM conv with tap-resident A tile, software-pipelined
// (T3+T4+T5): linear step index j = ic*16+kk (0..127).
//  - Bs: 3-buffer ring (3 x 8 KB), prefetch depth 2 (iter j stages j+2).
//    LDS total 33792 B -> 4 blocks/CU.
//  - One raw s_barrier per iter fused with counted s_waitcnt vmcnt(2):
//    B(j+1)'s 2 loads (older, in-order) complete, B(j+2)'s 2 stay in flight.
//    vmcnt(0) only at the 2 peeled final iters.
//  - Ring-3 race ledger (single barrier/iter => all waves in same iter j):
//    writes buf (j+2)%3, reads buf j%3 (distinct); old contents of
//    (j+2)%3 = B(j-1), whose reads completed before barrier_{j-1}.
//  - A restage at ic boundaries is DIRECT (load->cvt->ds_write, conservative
//    drain, 8/128 iters). Round-2 post-mortem: the T14 reg-prefetch variant
//    (a_pref[5] live across the MFMA phase) blew the 128-reg budget
//    (64 AGPR acc + 32 frag + 20 pref + addr) and spilled to scratch
//    (+27 MB HBM writes, MfmaUtil/Occ 1.31 -> 1.03). Direct staging keeps
//    nothing live across the hot phase; allocator serializes, not spills.
//  - s_setprio(1) around the 16-MFMA cluster.
//  - launch_bounds(256,4): 128 unified regs/thread = 64 AGPR + 64 arch -> 4
//    blocks/CU together with the 33792 B LDS.
// ---------------------------------------------------------------------------
__global__ void __launch_bounds__(256, 4) conv_mfma_kernel(const float* __restrict__ xg,
                                                           const __bf16* __restrict__ wt,
                                                           float* __restrict__ out) {
  __shared__ __align__(16) __bf16 As[144 * 32];       // [row t-local][32 ch] 9216 B
  __shared__ __align__(16) __bf16 Bs[3][128 * 32];    // ring of [row o-local][32 k] 3x8192 B

  const int bx = blockIdx.x;
  const int nb = bx & 1;          // o-block 0..1
  const int mb = (bx >> 1) & 15;  // t-block 0..15
  const int b  = bx >> 5;         // batch   0..31

  const int tid  = threadIdx.x;
  const int w    = tid >> 6;
  const int lane = tid & 63;
  const int wm   = w >> 1, wn = w & 1;
  const int n16  = lane & 15, q = lane >> 4;

  const int t0 = mb * 128;
  const int o0 = nb * 128;

  const float* xbase = xg + (size_t)b * (S_ * CIN_);

  // A staging geometry (reg round-trip): thread -> (row sr, 4 fp32 at col sc)
  const int sr = tid >> 3;        // 0..31
  const int sc = (tid & 7) * 4;   // fp32/bf16 col offset
  // B staging geometry (global_load_lds, 16B/lane): wave w, issue p covers
  // rows p*64 + w*16 .. +16
  const int br = w * 16 + (lane >> 2);
  const int bc = (lane & 3) * 8;

  f32x4 acc[4][4];
  #pragma unroll
  for (int im_ = 0; im_ < 4; im_++)
    #pragma unroll
    for (int in_ = 0; in_ < 4; in_++)
      acc[im_][in_] = {0.f, 0.f, 0.f, 0.f};

  // ---- Stage A for channel group ic: rows 0..143 (x rows t0.., clamped) ----
  auto stage_a = [&](int ic) {
    const float* xcol = xbase + ic * 32 + sc;
    #pragma unroll
    for (int p = 0; p < 4; p++) {
      int r = p * 32 + sr;
      int rg = t0 + r; rg = (rg < S_) ? rg : (S_ - 1);
      float4 v = *(const float4*)(xcol + (size_t)rg * CIN_);
      bf16x4 o4; o4[0]=(__bf16)v.x; o4[1]=(__bf16)v.y; o4[2]=(__bf16)v.z; o4[3]=(__bf16)v.w;
      *(bf16x4*)(As + r * 32 + sc) = o4;
    }
    if (tid < 128) {  // tail rows 128..143
      int r = 128 + sr;
      int rg = t0 + r; rg = (rg < S_) ? rg : (S_ - 1);
      float4 v = *(const float4*)(xcol + (size_t)rg * CIN_);
      bf16x4 o4; o4[0]=(__bf16)v.x; o4[1]=(__bf16)v.y; o4[2]=(__bf16)v.z; o4[3]=(__bf16)v.w;
      *(bf16x4*)(As + r * 32 + sc) = o4;
    }
  };

  // ---- Stage B chunk for step j into ring buffer buf (2 gload_lds/wave) ----
  auto stage_b = [&](int j, int buf) {
    const int kk = j & 15;
    const int i0 = (j >> 4) * 32;
    const __bf16* wcol = wt + (size_t)kk * CIN_ + i0 + bc;
    __bf16* dst = &Bs[0][0] + buf * (128 * 32) + (w * 16) * 32;
    #pragma unroll
    for (int p = 0; p < 2; p++) {
      int orow = o0 + p * 64 + br;
      gload_lds16(wcol + (size_t)orow * RTOT_, (void*)(dst + p * 64 * 32));
    }
  };

  // ---- Prologue: A(ic=0) + B(0), B(1); wait B(0) landed, keep B(1) in flight
  stage_a(0);
  stage_b(0, 0);
  stage_b(1, 1);
  asm volatile("s_waitcnt vmcnt(2) lgkmcnt(0)\n\ts_barrier" ::: "memory");

  int jr = 0;   // read buffer  = j % 3
  int jw = 2;   // write buffer = (j+2) % 3
  #pragma unroll 1
  for (int j = 0; j < 128; ++j) {
    const int kk = j & 15;

    if (j + 2 < 128) stage_b(j + 2, jw);   // prefetch depth 2 (wave-uniform)

    const __bf16* bsr = &Bs[0][0] + jr * (128 * 32);
    bf16x8 af[4], bfrag[4];
    #pragma unroll
    for (int jm = 0; jm < 4; jm++) {
      int row = kk + wm * 64 + jm * 16 + n16;    // A[m=lane&15][k=q*8+j]
      af[jm] = *(const bf16x8*)(As + row * 32 + q * 8);
    }
    #pragma unroll
    for (int jn = 0; jn < 4; jn++) {
      int row = wn * 64 + jn * 16 + n16;         // B^T[n=lane&15][k=q*8+j]
      bfrag[jn] = *(const bf16x8*)(bsr + row * 32 + q * 8);
    }

    __builtin_amdgcn_s_setprio(1);
    #pragma unroll
    for (int jm = 0; jm < 4; jm++)
      #pragma unroll
      for (int jn = 0; jn < 4; jn++)
        acc[jm][jn] = __builtin_amdgcn_mfma_f32_16x16x32_bf16(af[jm], bfrag[jn], acc[jm][jn], 0, 0, 0);
    __builtin_amdgcn_s_setprio(0);

    if (j == 127) break;               // last step: no barrier needed

    // Counted end-of-iter wait: B(j+1) complete (older), B(j+2) stays in
    // flight. j==126 issued nothing this iter -> must drain B(127) fully.
    if (j <= 125) asm volatile("s_waitcnt vmcnt(2)\n\ts_barrier" ::: "memory");
    else          asm volatile("s_waitcnt vmcnt(0)\n\ts_barrier" ::: "memory");

    if (kk == 15) {
      // ic boundary: all waves' As reads for this ic were pre-barrier -> safe
      // to overwrite. Direct restage (conservative drain, 8x/kernel).
      stage_a((j + 1) >> 4);
      asm volatile("s_waitcnt lgkmcnt(0)\n\ts_barrier" ::: "memory");
    }

    jr = (jr == 2) ? 0 : jr + 1;
    jw = (jw == 2) ? 0 : jw + 1;
  }

  // ---- Epilogue: C/D layout col = lane&15, row = (lane>>4)*4 + reg ----
  float* obase = out + (size_t)b * TOUT_ * COUT_;
  #pragma unroll
  for (int jm = 0; jm < 4; jm++) {
    #pragma unroll
    for (int r = 0; r < 4; r++) {
      int t = t0 + wm * 64 + jm * 16 + q * 4 + r;
      if (t < TOUT_) {
        float* orow = obase + (size_t)t * COUT_ + o0 + wn * 64 + n16;
        #pragma unroll
        for (int jn = 0; jn < 4; jn++)
          orow[jn * 16] = acc[jm][jn][r];
      }
    }
  }
}

// ---------------------------------------------------------------------------
extern "C" void kernel_launch(void* const* d_in, const int* in_sizes, int n_in,
                              void* d_out, int out_size, void* d_ws, size_t ws_size,
                              hipStream_t stream) {
  const float* x  = (const float*)d_in[0];
  const float* wr = (const float*)d_in[1];
  const float* wi = (const float*)d_in[2];
  const float* ph = (const float*)d_in[3];
  float* out = (float*)d_out;

  __bf16* wt = (__bf16*)d_ws;  // 2 MB only

  build_wt_kernel<<<dim3((COUT_ * CIN_) / 256), dim3(256), 0, stream>>>(wr, wi, ph, wt);
  conv_mfma_kernel<<<dim3(B_ * 16 * 2), dim3(256), 0, stream>>>(x, wt, out);
}

// Round 4
// 220.610 us; speedup vs baseline: 1.2237x; 1.0042x over previous
//
#include <hip/hip_runtime.h>
#include <math.h>

// Problem constants
#define B_    32
#define S_    2048
#define CIN_  256
#define COUT_ 256
#define K_    16
#define TOUT_ 2033   // S - K + 1
#define RTOT_ 4096   // CIN * K reduction length

typedef __bf16 bf16x4 __attribute__((ext_vector_type(4)));
typedef __bf16 bf16x8 __attribute__((ext_vector_type(8)));
typedef float  f32x4  __attribute__((ext_vector_type(4)));

#define GLOBAL_AS __attribute__((address_space(1)))
#define LDS_AS    __attribute__((address_space(3)))

__device__ __forceinline__ void gload_lds16(const void* g, void* l) {
  // async global -> LDS: per-lane global gather, LDS dest = wave-uniform base + lane*16
  __builtin_amdgcn_global_load_lds((const GLOBAL_AS void*)g, (LDS_AS void*)l, 16, 0, 0);
}

// ---------------------------------------------------------------------------
// Build B^T in bf16:  wt[o][kk*256 + i] = cos(ph[kk])*w_real[o][i][kk]
//                                        - sin(ph[kk])*w_imag[o][i][kk]
// Row-major [COUT][RTOT] = 2 MB workspace (keep ws footprint tiny).
// ---------------------------------------------------------------------------
__global__ void __launch_bounds__(256) build_wt_kernel(const float* __restrict__ wr,
                                                       const float* __restrict__ wi,
                                                       const float* __restrict__ ph,
                                                       __bf16* __restrict__ wt) {
  int t = blockIdx.x * 256 + threadIdx.x;   // 65536 threads: one per (o,i)
  int o = t >> 8, i = t & 255;
  const float4* wr4 = (const float4*)(wr + (size_t)(o * CIN_ + i) * K_);
  const float4* wi4 = (const float4*)(wi + (size_t)(o * CIN_ + i) * K_);
  float re[16], im[16];
  #pragma unroll
  for (int v = 0; v < 4; v++) {
    float4 a = wr4[v];
    re[4*v+0]=a.x; re[4*v+1]=a.y; re[4*v+2]=a.z; re[4*v+3]=a.w;
    float4 b = wi4[v];
    im[4*v+0]=b.x; im[4*v+1]=b.y; im[4*v+2]=b.z; im[4*v+3]=b.w;
  }
  #pragma unroll
  for (int kk = 0; kk < K_; kk++) {
    float p = ph[kk];
    wt[(size_t)o * RTOT_ + kk * CIN_ + i] = (__bf16)(cosf(p)*re[kk] - sinf(p)*im[kk]);
  }
}

// ---------------------------------------------------------------------------
// Main: implicit-GEMM conv, software-pipelined (T3+T4+T5) + T2 XOR-swizzle.
//
// T2 swizzle (round-4): LDS rows are 32 bf16 = 64 B = 16 banks, so an
// unswizzled fragment read (byte = row*64 + q*16) gives a 16-lane quarter
// only 8 distinct banks -> 4-way conflict on every ds_read_b128 (measured
// 1.678e7 = 4 extra cyc/read, LDS the critical pipe: 1536 vs MFMA 1248
// cyc/CU/iter-round). Fix: involution  byte ^= ((row>>1)&3) << 4
// (XOR 16B-slot bits [5:4] with row bits [2:1]) -> 2-way (free).
//   - As (reg-staged): swizzled ds_write offset + swizzled read slot.
//   - Bs (global_load_lds writes LINEARLY; rule #21 both-sides-or-neither):
//     pre-swizzle the GLOBAL source per lane: dest slot = l&3, dest row
//     bits[2:1] = (l>>3)&3  =>  source slot = (l&3) ^ ((l>>3)&3).
//     Same 64B line set per 4-lane group -> coalescing unchanged.
//   - Read slots: aswz = ((kk+n16)>>1)&3 (jm*16/wm*64 don't touch bits 1-2),
//     bswz = (n16>>1)&3.
//
// Pipeline (unchanged from round 3):
//  - Bs 3-ring (3x8 KB), prefetch depth 2; LDS 33792 B -> 4 blocks/CU.
//  - One s_barrier/iter fused with counted s_waitcnt vmcnt(2); vmcnt(0)
//    only at the 2 peeled final iters.
//  - Race ledger: writes buf (j+2)%3, reads buf j%3; old contents of
//    (j+2)%3 = B(j-1), consumed before barrier_{j-1}.
//  - A restage DIRECT at ic boundaries (T14 reg-prefetch spilled: round 2).
//  - s_setprio(1) around the 16-MFMA cluster; launch_bounds(256,4).
// ---------------------------------------------------------------------------
__global__ void __launch_bounds__(256, 4) conv_mfma_kernel(const float* __restrict__ xg,
                                                           const __bf16* __restrict__ wt,
                                                           float* __restrict__ out) {
  __shared__ __align__(16) __bf16 As[144 * 32];       // [row t-local][32 ch] 9216 B
  __shared__ __align__(16) __bf16 Bs[3][128 * 32];    // ring of [row o-local][32 k] 3x8192 B

  const int bx = blockIdx.x;
  const int nb = bx & 1;          // o-block 0..1
  const int mb = (bx >> 1) & 15;  // t-block 0..15
  const int b  = bx >> 5;         // batch   0..31

  const int tid  = threadIdx.x;
  const int w    = tid >> 6;
  const int lane = tid & 63;
  const int wm   = w >> 1, wn = w & 1;
  const int n16  = lane & 15, q = lane >> 4;

  const int t0 = mb * 128;
  const int o0 = nb * 128;

  const float* xbase = xg + (size_t)b * (S_ * CIN_);

  // A staging geometry (reg round-trip): thread -> (row sr, 4 fp32 at col sc)
  const int sr = tid >> 3;        // 0..31
  const int sc = (tid & 7) * 4;   // fp32/bf16 col offset (8B chunk; slot = sc>>3)
  // B staging geometry (global_load_lds, 16B/lane): wave w, issue p covers
  // rows p*64 + w*16 .. +16. Source slot carries the T2 pre-swizzle.
  const int br = w * 16 + (lane >> 2);
  const int bc = (((lane & 3) ^ ((lane >> 3) & 3))) * 8;   // T2 pre-swizzled source slot

  // T2 read-side slot swizzles (hoisted; row bits [2:1])
  const int bswz = (n16 >> 1) & 3;                 // Bs rows = wn*64+jn*16+n16

  f32x4 acc[4][4];
  #pragma unroll
  for (int im_ = 0; im_ < 4; im_++)
    #pragma unroll
    for (int in_ = 0; in_ < 4; in_++)
      acc[im_][in_] = {0.f, 0.f, 0.f, 0.f};

  // ---- Stage A for channel group ic: rows 0..143 (x rows t0.., clamped) ----
  // T2: 8B chunk (orig col sc) lands at col sc ^ (((r>>1)&3)<<3).
  auto stage_a = [&](int ic) {
    const float* xcol = xbase + ic * 32 + sc;
    #pragma unroll
    for (int p = 0; p < 4; p++) {
      int r = p * 32 + sr;
      int rg = t0 + r; rg = (rg < S_) ? rg : (S_ - 1);
      float4 v = *(const float4*)(xcol + (size_t)rg * CIN_);
      bf16x4 o4; o4[0]=(__bf16)v.x; o4[1]=(__bf16)v.y; o4[2]=(__bf16)v.z; o4[3]=(__bf16)v.w;
      *(bf16x4*)(As + r * 32 + (sc ^ (((r >> 1) & 3) << 3))) = o4;
    }
    if (tid < 128) {  // tail rows 128..143
      int r = 128 + sr;
      int rg = t0 + r; rg = (rg < S_) ? rg : (S_ - 1);
      float4 v = *(const float4*)(xcol + (size_t)rg * CIN_);
      bf16x4 o4; o4[0]=(__bf16)v.x; o4[1]=(__bf16)v.y; o4[2]=(__bf16)v.z; o4[3]=(__bf16)v.w;
      *(bf16x4*)(As + r * 32 + (sc ^ (((r >> 1) & 3) << 3))) = o4;
    }
  };

  // ---- Stage B chunk for step j into ring buffer buf (2 gload_lds/wave) ----
  // T2: source column pre-swizzled via bc so the LINEAR LDS write yields the
  // swizzled tile (content at [row][slot] = orig slot ^ ((row>>1)&3)).
  auto stage_b = [&](int j, int buf) {
    const int kk = j & 15;
    const int i0 = (j >> 4) * 32;
    const __bf16* wcol = wt + (size_t)kk * CIN_ + i0 + bc;
    __bf16* dst = &Bs[0][0] + buf * (128 * 32) + (w * 16) * 32;
    #pragma unroll
    for (int p = 0; p < 2; p++) {
      int orow = o0 + p * 64 + br;
      gload_lds16(wcol + (size_t)orow * RTOT_, (void*)(dst + p * 64 * 32));
    }
  };

  // ---- Prologue: A(ic=0) + B(0), B(1); wait B(0) landed, keep B(1) in flight
  stage_a(0);
  stage_b(0, 0);
  stage_b(1, 1);
  asm volatile("s_waitcnt vmcnt(2) lgkmcnt(0)\n\ts_barrier" ::: "memory");

  int jr = 0;   // read buffer  = j % 3
  int jw = 2;   // write buffer = (j+2) % 3
  #pragma unroll 1
  for (int j = 0; j < 128; ++j) {
    const int kk = j & 15;

    if (j + 2 < 128) stage_b(j + 2, jw);   // prefetch depth 2 (wave-uniform)

    const __bf16* bsr = &Bs[0][0] + jr * (128 * 32);
    const int aswz = ((kk + n16) >> 1) & 3;   // As row bits[2:1] (uniform over jm)
    bf16x8 af[4], bfrag[4];
    #pragma unroll
    for (int jm = 0; jm < 4; jm++) {
      int row = kk + wm * 64 + jm * 16 + n16;    // A[m=lane&15][k=q*8+j]
      af[jm] = *(const bf16x8*)(As + row * 32 + ((q ^ aswz) * 8));
    }
    #pragma unroll
    for (int jn = 0; jn < 4; jn++) {
      int row = wn * 64 + jn * 16 + n16;         // B^T[n=lane&15][k=q*8+j]
      bfrag[jn] = *(const bf16x8*)(bsr + row * 32 + ((q ^ bswz) * 8));
    }

    __builtin_amdgcn_s_setprio(1);
    #pragma unroll
    for (int jm = 0; jm < 4; jm++)
      #pragma unroll
      for (int jn = 0; jn < 4; jn++)
        acc[jm][jn] = __builtin_amdgcn_mfma_f32_16x16x32_bf16(af[jm], bfrag[jn], acc[jm][jn], 0, 0, 0);
    __builtin_amdgcn_s_setprio(0);

    if (j == 127) break;               // last step: no barrier needed

    // Counted end-of-iter wait: B(j+1) complete (older), B(j+2) stays in
    // flight. j==126 issued nothing this iter -> must drain B(127) fully.
    if (j <= 125) asm volatile("s_waitcnt vmcnt(2)\n\ts_barrier" ::: "memory");
    else          asm volatile("s_waitcnt vmcnt(0)\n\ts_barrier" ::: "memory");

    if (kk == 15) {
      // ic boundary: all waves' As reads for this ic were pre-barrier -> safe
      // to overwrite. Direct restage (conservative drain, 8x/kernel).
      stage_a((j + 1) >> 4);
      asm volatile("s_waitcnt lgkmcnt(0)\n\ts_barrier" ::: "memory");
    }

    jr = (jr == 2) ? 0 : jr + 1;
    jw = (jw == 2) ? 0 : jw + 1;
  }

  // ---- Epilogue: C/D layout col = lane&15, row = (lane>>4)*4 + reg ----
  float* obase = out + (size_t)b * TOUT_ * COUT_;
  #pragma unroll
  for (int jm = 0; jm < 4; jm++) {
    #pragma unroll
    for (int r = 0; r < 4; r++) {
      int t = t0 + wm * 64 + jm * 16 + q * 4 + r;
      if (t < TOUT_) {
        float* orow = obase + (size_t)t * COUT_ + o0 + wn * 64 + n16;
        #pragma unroll
        for (int jn = 0; jn < 4; jn++)
          orow[jn * 16] = acc[jm][jn][r];
      }
    }
  }
}

// ---------------------------------------------------------------------------
extern "C" void kernel_launch(void* const* d_in, const int* in_sizes, int n_in,
                              void* d_out, int out_size, void* d_ws, size_t ws_size,
                              hipStream_t stream) {
  const float* x  = (const float*)d_in[0];
  const float* wr = (const float*)d_in[1];
  const float* wi = (const float*)d_in[2];
  const float* ph = (const float*)d_in[3];
  float* out = (float*)d_out;

  __bf16* wt = (__bf16*)d_ws;  // 2 MB only

  build_wt_kernel<<<dim3((COUT_ * CIN_) / 256), dim3(256), 0, stream>>>(wr, wi, ph, wt);
  conv_mfma_kernel<<<dim3(B_ * 16 * 2), dim3(256), 0, stream>>>(x, wt, out);
}